// Round 5
// baseline (508.813 us; speedup 1.0000x reference)
//
#include <hip/hip_runtime.h>

typedef unsigned short u16;
typedef unsigned char  u8;
typedef unsigned long long u64;

using bf16x8 = __attribute__((ext_vector_type(8))) short;
using f32x4  = __attribute__((ext_vector_type(4))) float;

static __device__ __forceinline__ u16 f2bf(float f) {
  union { float f; unsigned u; } v; v.f = f;
  unsigned r = v.u + 0x7fffu + ((v.u >> 16) & 1u);   // RNE
  return (u16)(r >> 16);
}

// async global->LDS, 16B per lane. LDS dest must be wave-uniform base + lane*16.
static __device__ __forceinline__ void gload_lds16(const void* g, void* l) {
  __builtin_amdgcn_global_load_lds((const __attribute__((address_space(1))) void*)g,
                                   (__attribute__((address_space(3))) void*)l, 16, 0, 0);
}

// ---------------- f32 -> bf16 convert (vectorized) ----------------
__global__ __launch_bounds__(256) void cvt_bf16_kernel(const float4* __restrict__ in,
                                                       ushort4* __restrict__ out, int n4) {
  int i = blockIdx.x * 256 + threadIdx.x;
  if (i >= n4) return;
  float4 v = in[i];
  ushort4 o;
  o.x = f2bf(v.x); o.y = f2bf(v.y); o.z = f2bf(v.z); o.w = f2bf(v.w);
  out[i] = o;
}

// ---------------- zero-fill fallback (ws too small diagnostic) ----------------
__global__ __launch_bounds__(256) void zero_out_kernel(float* __restrict__ out, int n) {
  int i = blockIdx.x * 256 + threadIdx.x;
  if (i < n) out[i] = 0.f;
}

// ---------------- mask layout detection + bit-packing ----------------
// JAX bool may land as u8 (1B) or int32 (4B) — harness doc is ambiguous.
// int32 0/1 little-endian => bytes at i%4!=0 are all zero. u8 random 0/1 =>
// nonzero at such positions w.p. 1 - 2^-3072 over the first 4096 bytes.
__global__ void mask_detect_kernel(const u8* __restrict__ mask, int* __restrict__ flag) {
  __shared__ int nz;
  if (threadIdx.x == 0) nz = 0;
  __syncthreads();
  int cnt = 0;
  for (int i = threadIdx.x; i < 4096; i += 256)
    if ((i & 3) && mask[i]) cnt++;
  if (cnt) atomicAdd(&nz, cnt);
  __syncthreads();
  if (threadIdx.x == 0) *flag = (nz == 0) ? 1 : 0;   // 1 => int32 layout
}

// Pack mask into u64 words via wave ballot: word w bit i = mask[w*64+i]!=0.
// 1MB of u8 loads in attn -> 128KB of broadcast u64 loads.
__global__ __launch_bounds__(256) void mask_pack_kernel(const void* __restrict__ mask,
                                                        u64* __restrict__ out,
                                                        const int* __restrict__ flag, int nwords) {
  int w = blockIdx.x * 4 + (threadIdx.x >> 6);
  int lane = threadIdx.x & 63;
  if (w >= nwords) return;
  int idx = w * 64 + lane;
  int m;
  if (*flag) m = ((const int*)mask)[idx] != 0;
  else       m = ((const u8*)mask)[idx] != 0;
  u64 bits = __ballot(m != 0);
  if (lane == 0) out[w] = bits;
}

// ---------------- bf16 BT-GEMM: C[M,N] = A[M,K] * B[N,K]^T + bias ----------------
// 128x128 tile, BK=64, 4 waves (2x2), each wave 64x64 via 4x4 frags of 16x16x32.
// m97 structure (874 TF verified); T2 swizzle deliberately NOT applied (measured
// null on the 2-phase 128^2 structure — m228d regime gate).
template<bool OUT_BF16>
__global__ __launch_bounds__(256, 2)
void gemm_bt(const u16* __restrict__ A, const u16* __restrict__ Bm,
             const float* __restrict__ bias, void* __restrict__ Cout,
             int M, int N, int K) {
  constexpr int BK = 64;
  __shared__ u16 lA[128 * BK];
  __shared__ u16 lB[128 * BK];
  const int tid = threadIdx.x;
  const int wv = tid >> 6, lane = tid & 63;
  const int wr = (wv >> 1) * 64, wc = (wv & 1) * 64;
  const int bm = blockIdx.x * 128, bn = blockIdx.y * 128;
  const int frow = lane & 15, fk = (lane >> 4) * 8;
  const int srow = tid >> 3;          // 0..31 staging row
  const int scol = (tid & 7) * 8;     // staging col (elements)
  const u16* ga = A + (size_t)(bm + srow) * K + scol;
  const u16* gb = Bm + (size_t)(bn + srow) * K + scol;
  u16* la = &lA[srow * BK + scol];
  u16* lb = &lB[srow * BK + scol];

  f32x4 acc[4][4] = {};

  for (int k0 = 0; k0 < K; k0 += BK) {
#pragma unroll
    for (int r = 0; r < 4; ++r) {
      gload_lds16(ga + (size_t)(r * 32) * K + k0, la + r * 32 * BK);
      gload_lds16(gb + (size_t)(r * 32) * K + k0, lb + r * 32 * BK);
    }
    __syncthreads();
#pragma unroll
    for (int kk = 0; kk < 2; ++kk) {
      bf16x8 af[4], bf[4];
#pragma unroll
      for (int m = 0; m < 4; ++m)
        af[m] = *(const bf16x8*)&lA[(wr + m * 16 + frow) * BK + kk * 32 + fk];
#pragma unroll
      for (int n = 0; n < 4; ++n)
        bf[n] = *(const bf16x8*)&lB[(wc + n * 16 + frow) * BK + kk * 32 + fk];
#pragma unroll
      for (int m = 0; m < 4; ++m)
#pragma unroll
        for (int n = 0; n < 4; ++n)
          acc[m][n] = __builtin_amdgcn_mfma_f32_16x16x32_bf16(af[m], bf[n], acc[m][n], 0, 0, 0);
    }
    __syncthreads();
  }
  // epilogue: C/D layout col=lane&15, row=(lane>>4)*4+reg  [m89/m91 verified]
#pragma unroll
  for (int n = 0; n < 4; ++n) {
    const int col = bn + wc + n * 16 + frow;
    const float bv = bias[col];
#pragma unroll
    for (int m = 0; m < 4; ++m) {
      const int row0 = bm + wr + m * 16 + (lane >> 4) * 4;
#pragma unroll
      for (int r = 0; r < 4; ++r) {
        float v = acc[m][n][r] + bv;
        if constexpr (OUT_BF16)
          ((u16*)Cout)[(size_t)(row0 + r) * N + col] = f2bf(v);
        else
          ((float*)Cout)[(size_t)(row0 + r) * N + col] = v;
      }
    }
  }
}

// ---------------- flash attention with prev-bias + packed bool mask ----------------
// grid = B*H*16 blocks; block = (b,h,qt) handles 64 q-rows. 4 waves, wave w owns
// q-rows w*16..w*16+15. K/V tiles of 64 staged per iteration; online softmax in fp32.
//
// LDS swizzles (all both-sides involutions, rule #21):
//  lQ/lK: rows are 128B = 0 mod 32 banks -> naive frag read uses 16 banks (2x floor).
//    Fix: stage with pre-swizzled GLOBAL column (scol8 ^ ((srow&7)<<3)), linear LDS
//    dest; read col' = col ^ ((frow&7)<<3). Post-swizzle: 32 banks, 8 dwords/bank.
//  lVT: V^T, elem(d,k) -> lVT[d*64 + (k ^ (((d>>3)&7)<<3))]; writes 32 banks
//    2-lanes-per-dword (free), reads at data floor.
//
// prev (256MB) is the roofline floor (~41us). Its loads are issued AFTER the
// staging barrier: no LDS dependence, so they overlap this wave's own QK^T phase
// instead of being drained by the barrier's vmcnt(0) (T14 issue-early/use-late).
// __launch_bounds__(256,4): TLP for the remaining latency; needs <=128 VGPR.
__global__ __launch_bounds__(256, 4)
void attn_kernel(const u16* __restrict__ qkv,   // [4096][3072] bf16 (h*192 + {q,k,v})
                 const float* __restrict__ prev,
                 const u64* __restrict__ mbits, // packed mask [S][S/64]
                 u16* __restrict__ vals) {      // [4096][1024] bf16
  constexpr int S = 1024;
  __shared__ u16 lQ[64 * 64];
  __shared__ u16 lK[64 * 64];
  __shared__ u16 lVT[64 * 64];      // [d][k_swizzled]
  __shared__ u16 lP[4][16 * 72];    // per-wave P [q][k], stride 72
  const int tid = threadIdx.x, wv = tid >> 6, lane = tid & 63;
  const int bh = blockIdx.x >> 4;          // b*16+h
  const int qt = blockIdx.x & 15;
  const int b = bh >> 4, h = bh & 15;
  const int frow = lane & 15, fkg = lane >> 4, fk = fkg * 8;
  const int srow = tid >> 3, scol8 = (tid & 7) * 8;
  const size_t rowQ0 = (size_t)(b * S + qt * 64);

  // staging-side swizzled global column (same for Q and K; (srow+32)&7 == srow&7)
  const int scol_sw = scol8 ^ ((srow & 7) << 3);
  // read-side swizzled columns for QK^T frags (loop-invariant)
  const int c0 = fk ^ ((frow & 7) << 3);          // kk=0
  const int c1 = (fk + 32) ^ ((frow & 7) << 3);   // kk=1

  // stage Q once (pre-swizzled source -> linear LDS dest)
  {
    const u16* g = qkv + (rowQ0 + srow) * 3072 + h * 192 + scol_sw;
    gload_lds16(g, &lQ[srow * 64 + scol8]);
    gload_lds16(g + (size_t)32 * 3072, &lQ[(srow + 32) * 64 + scol8]);
  }
  __syncthreads();
  bf16x8 qf0 = *(const bf16x8*)&lQ[(wv * 16 + frow) * 64 + c0];
  bf16x8 qf1 = *(const bf16x8*)&lQ[(wv * 16 + frow) * 64 + c1];

  float m_run[4], l_run[4];
  f32x4 acc_o[4] = {};
#pragma unroll
  for (int r = 0; r < 4; ++r) { m_run[r] = -3e38f; l_run[r] = 0.f; }

  const int qloc = wv * 16 + fkg * 4;   // this lane's q-row base (regs r=0..3)
  const float* prow = prev + ((size_t)bh * S + qt * 64 + qloc) * S;
  const u64* mrow = mbits + (size_t)(qt * 64 + qloc) * (S / 64);

  // V-swizzle constant for this lane (staging side): d = scol8+j => d>>3 == tid&7
  const int vsw = (tid & 7) << 3;

  for (int kt = 0; kt < 16; ++kt) {
    __syncthreads();   // previous tile fully consumed
    {  // stage K tile (pre-swizzled source -> linear LDS dest, async)
      const u16* g = qkv + (size_t)(b * S + kt * 64 + srow) * 3072 + h * 192 + 64 + scol_sw;
      gload_lds16(g, &lK[srow * 64 + scol8]);
      gload_lds16(g + (size_t)32 * 3072, &lK[(srow + 32) * 64 + scol8]);
    }
    // V global reads (regs) — consumed by lVT writes before the staging barrier
    const u16* gv = qkv + (size_t)(b * S + kt * 64 + srow) * 3072 + h * 192 + 128 + scol8;
    bf16x8 v0 = *(const bf16x8*)gv;
    bf16x8 v1 = *(const bf16x8*)(gv + (size_t)32 * 3072);
    {  // V^T scatter to LDS with k-swizzle (conflict-free: 32 banks, 2 lanes/dword)
      const int k0 = srow ^ vsw;
      const int k1 = (srow + 32) ^ vsw;
#pragma unroll
      for (int j = 0; j < 8; ++j) {
        lVT[(scol8 + j) * 64 + k0] = (u16)v0[j];
        lVT[(scol8 + j) * 64 + k1] = (u16)v1[j];
      }
    }
    __syncthreads();   // staging complete (drains gload_lds + ds_writes)
    // Issue prev + mask loads NOW — after the barrier so their ~900cy HBM latency
    // overlaps this wave's QK^T ds_reads+MFMAs instead of the barrier drain.
    const float* pp = prow + kt * 64 + frow;
    float pvraw[4][4];
    u64 mw[4];
#pragma unroll
    for (int r = 0; r < 4; ++r) mw[r] = mrow[r * (S / 64) + kt];
#pragma unroll
    for (int n = 0; n < 4; ++n)
#pragma unroll
      for (int r = 0; r < 4; ++r)
        pvraw[n][r] = pp[(size_t)r * S + n * 16];
    // S = Q K^T  (BT-form; swizzled frag reads, full 32-bank spread)
    f32x4 s[4];
#pragma unroll
    for (int n = 0; n < 4; ++n) {
      bf16x8 kf0 = *(const bf16x8*)&lK[(n * 16 + frow) * 64 + c0];
      bf16x8 kf1 = *(const bf16x8*)&lK[(n * 16 + frow) * 64 + c1];
      f32x4 z = {0.f, 0.f, 0.f, 0.f};
      z = __builtin_amdgcn_mfma_f32_16x16x32_bf16(qf0, kf0, z, 0, 0, 0);
      s[n] = __builtin_amdgcn_mfma_f32_16x16x32_bf16(qf1, kf1, z, 0, 0, 0);
    }
    // scores = s/32 + prev, masked -> -1e30 (fold at use; exact in fp32)
#pragma unroll
    for (int r = 0; r < 4; ++r) {
      const u64 t = mw[r] >> frow;   // bit n*16 of t == mask bit n*16+frow
#pragma unroll
      for (int n = 0; n < 4; ++n) {
        float sc = s[n][r] * 0.03125f + pvraw[n][r];
        s[n][r] = ((t >> (n * 16)) & 1ull) ? -1e30f : sc;
      }
    }
    // row max across 16 lanes (cols) + 4 frags
    float tmax[4];
#pragma unroll
    for (int r = 0; r < 4; ++r) {
      float t = fmaxf(fmaxf(s[0][r], s[1][r]), fmaxf(s[2][r], s[3][r]));
      t = fmaxf(t, __shfl_xor(t, 1));
      t = fmaxf(t, __shfl_xor(t, 2));
      t = fmaxf(t, __shfl_xor(t, 4));
      t = fmaxf(t, __shfl_xor(t, 8));
      tmax[r] = t;
    }
    // online softmax update
    float psum[4];
#pragma unroll
    for (int r = 0; r < 4; ++r) {
      float mnew = fmaxf(m_run[r], tmax[r]);
      float sc = __expf(m_run[r] - mnew);
      m_run[r] = mnew;
      l_run[r] *= sc;
#pragma unroll
      for (int dn = 0; dn < 4; ++dn) acc_o[dn][r] *= sc;
      float ps = 0.f;
#pragma unroll
      for (int n = 0; n < 4; ++n) {
        float p = __expf(s[n][r] - mnew);
        s[n][r] = p;
        ps += p;
      }
      psum[r] = ps;
    }
#pragma unroll
    for (int r = 0; r < 4; ++r) {
      float t = psum[r];
      t += __shfl_xor(t, 1); t += __shfl_xor(t, 2);
      t += __shfl_xor(t, 4); t += __shfl_xor(t, 8);
      l_run[r] += t;
    }
    // P -> per-wave LDS (bf16), transposing frag layout to A-operand layout
    u16* pw = &lP[wv][0];
#pragma unroll
    for (int n = 0; n < 4; ++n)
#pragma unroll
      for (int r = 0; r < 4; ++r)
        pw[(fkg * 4 + r) * 72 + n * 16 + frow] = f2bf(s[n][r]);
    bf16x8 pf0 = *(const bf16x8*)&pw[frow * 72 + fk];
    bf16x8 pf1 = *(const bf16x8*)&pw[frow * 72 + 32 + fk];
    // O += P V   (B-operand from swizzled transposed V)
#pragma unroll
    for (int dn = 0; dn < 4; ++dn) {
      const int d = dn * 16 + frow;
      const int sw = ((dn * 2 + (frow >> 3)) & 7) << 3;   // ((d>>3)&7)<<3
      bf16x8 vt0 = *(const bf16x8*)&lVT[d * 64 + (fk ^ sw)];
      bf16x8 vt1 = *(const bf16x8*)&lVT[d * 64 + ((fk + 32) ^ sw)];
      acc_o[dn] = __builtin_amdgcn_mfma_f32_16x16x32_bf16(pf0, vt0, acc_o[dn], 0, 0, 0);
      acc_o[dn] = __builtin_amdgcn_mfma_f32_16x16x32_bf16(pf1, vt1, acc_o[dn], 0, 0, 0);
    }
  }
  // epilogue: vals[b*S + q][h*64 + d] = O / l
#pragma unroll
  for (int r = 0; r < 4; ++r) {
    float inv = 1.0f / l_run[r];
    size_t row = (rowQ0 + qloc + r) * 1024 + h * 64;
#pragma unroll
    for (int dn = 0; dn < 4; ++dn)
      vals[row + dn * 16 + frow] = f2bf(acc_o[dn][r] * inv);
  }
}

extern "C" void kernel_launch(void* const* d_in, const int* in_sizes, int n_in,
                              void* d_out, int out_size, void* d_ws, size_t ws_size,
                              hipStream_t stream) {
  const float* x     = (const float*)d_in[0];
  const void*  mask  = d_in[1];                // layout detected on device
  const float* prev  = (const float*)d_in[2];
  const float* qkv_w = (const float*)d_in[3];
  const float* qkv_b = (const float*)d_in[4];
  const float* o_w   = (const float*)d_in[5];
  const float* o_b   = (const float*)d_in[6];

  // ws guard: if scratch is smaller than our 38MB layout, emit zeros instead of
  // OOB-writing (turns a would-be container crash into a clean mismatch signal).
  const size_t WS_NEEDED = 14680064 + 25165824;
  if (ws_size < WS_NEEDED) {
    zero_out_kernel<<<(out_size + 255) / 256, 256, 0, stream>>>((float*)d_out, out_size);
    return;
  }

  char* ws = (char*)d_ws;
  // region A [0, 8MB): x_bf16, later reused for vals_bf16
  u16* x_bf  = (u16*)(ws);
  u16* vals  = (u16*)(ws);
  // region B [8MB, 14MB): qkv_w bf16 during gemm1; afterwards subdivided:
  //   [8MB, 10MB)      o_w bf16
  //   [10MB, 10.125MB) packed mask bits (u64[16384])
  //   [11MB, ...)      detection flag
  u16* qw_bf   = (u16*)(ws + 8388608);
  u16* ow_bf   = (u16*)(ws + 8388608);
  u64* mask_b  = (u64*)(ws + 10485760);
  int* mflag   = (int*)(ws + 11534336);
  // region C [14MB, 38MB): qkv output bf16 [4096][3072]
  u16* qkv_o = (u16*)(ws + 14680064);

  cvt_bf16_kernel<<<4096, 256, 0, stream>>>((const float4*)x, (ushort4*)x_bf, 1048576);
  cvt_bf16_kernel<<<3072, 256, 0, stream>>>((const float4*)qkv_w, (ushort4*)qw_bf, 786432);

  dim3 g1(32, 24);
  gemm_bt<true><<<g1, 256, 0, stream>>>(x_bf, qw_bf, qkv_b, qkv_o, 4096, 3072, 1024);

  // region-B reuse below is stream-ordered after gemm1
  cvt_bf16_kernel<<<1024, 256, 0, stream>>>((const float4*)o_w, (ushort4*)ow_bf, 262144);
  mask_detect_kernel<<<1, 256, 0, stream>>>((const u8*)mask, mflag);
  mask_pack_kernel<<<4096, 256, 0, stream>>>(mask, mask_b, mflag, 16384);

  attn_kernel<<<1024, 256, 0, stream>>>(qkv_o, prev, mask_b, vals);

  dim3 g2(32, 8);
  gemm_bt<false><<<g2, 256, 0, stream>>>(vals, ow_bf, o_b, d_out, 4096, 1024, 1024);
}